// Round 5
// baseline (416.021 us; speedup 1.0000x reference)
//
#include <hip/hip_runtime.h>

#define V 128
#define D 20
#define NUM_EMB (V * V * V)
#define NBUCK 4096   // 16^3 coarse blocks: bucket = (cell >> 3) per dim
#define BCAP  512    // slots/bucket; mean occupancy 244, sd ~16 (17 sigma)

typedef float v4f __attribute__((ext_vector_type(4)));
typedef unsigned int u32;

// ---- per-(point,chunk) compute: byte-for-byte the verified round-0 body ----
__device__ __forceinline__ void compute_chunk(
    const float* __restrict__ x, const float* __restrict__ grid,
    float* __restrict__ out, int i, int k)
{
    float px = x[3 * i + 0];
    float py = x[3 * i + 1];
    float pz = x[3 * i + 2];

    // gp = floor((p+1)*64); cell spacing is exactly 1/64 in fp32
    int ix = (int)floorf((px + 1.0f) * 64.0f);
    int iy = (int)floorf((py + 1.0f) * 64.0f);
    int iz = (int)floorf((pz + 1.0f) * 64.0f);

    float x1 = (float)ix * (2.0f / 128.0f) - 1.0f;
    float x2 = (float)(ix + 1) * (2.0f / 128.0f) - 1.0f;
    float y1 = (float)iy * (2.0f / 128.0f) - 1.0f;
    float y2 = (float)(iy + 1) * (2.0f / 128.0f) - 1.0f;
    float z1 = (float)iz * (2.0f / 128.0f) - 1.0f;
    float z2 = (float)(iz + 1) * (2.0f / 128.0f) - 1.0f;

    float wx1 = (px - x1) * 64.0f, wx0 = (x2 - px) * 64.0f;
    float wy1 = (py - y1) * 64.0f, wy0 = (y2 - py) * 64.0f;
    float wz1 = (pz - z1) * 64.0f, wz0 = (z2 - pz) * 64.0f;

    int f000 = ix + iy * V + iz * V * V;

    int flats[8];
    flats[0] = f000;
    flats[1] = f000 + 1;
    flats[2] = f000 + V;
    flats[3] = f000 + V + 1;
    flats[4] = f000 + V * V;
    flats[5] = f000 + V * V + 1;
    flats[6] = f000 + V * V + V;
    flats[7] = f000 + V * V + V + 1;

    // JAX gather clamps OOB flat indices (boundary cells at 127)
    #pragma unroll
    for (int c = 0; c < 8; c++) {
        if (flats[c] > NUM_EMB - 1) flats[c] = NUM_EMB - 1;
    }

    float w[8];
    w[0] = wx0 * wy0 * wz0;
    w[1] = wx1 * wy0 * wz0;
    w[2] = wx0 * wy1 * wz0;
    w[3] = wx1 * wy1 * wz0;
    w[4] = wx0 * wy0 * wz1;
    w[5] = wx1 * wy0 * wz1;
    w[6] = wx0 * wy1 * wz1;
    w[7] = wx1 * wy1 * wz1;

    v4f q[8];
    #pragma unroll
    for (int c = 0; c < 8; c++) {
        q[c] = *(const v4f*)(grid + (size_t)flats[c] * D + 4 * k);
    }

    v4f acc = (v4f)(0.0f);
    #pragma unroll
    for (int c = 0; c < 8; c++) {
        acc += w[c] * q[c];
    }

    __builtin_nontemporal_store(acc, (v4f*)(out + (size_t)i * D + 4 * k));
}

// ---- pass 1: bin points by coarse cell ------------------------------------
__global__ __launch_bounds__(256) void bin_kernel(
    const float* __restrict__ x, const float* __restrict__ grid,
    float* __restrict__ out, u32* __restrict__ cnt, u32* __restrict__ bucket,
    int N)
{
    int i = blockIdx.x * 256 + threadIdx.x;
    if (i >= N) return;
    float px = x[3 * i + 0];
    float py = x[3 * i + 1];
    float pz = x[3 * i + 2];
    int ix = (int)floorf((px + 1.0f) * 64.0f);
    int iy = (int)floorf((py + 1.0f) * 64.0f);
    int iz = (int)floorf((pz + 1.0f) * 64.0f);
    int b = (ix >> 3) + ((iy >> 3) << 4) + ((iz >> 3) << 8);
    u32 pos = atomicAdd(&cnt[b], 1u);
    if (pos < BCAP) {
        bucket[(size_t)b * BCAP + pos] = (u32)i;
    } else {
        // statistically never (17 sigma), but correctness must not depend on
        // bucket capacity: compute the dropped point inline.
        for (int k = 0; k < 5; k++) compute_chunk(x, grid, out, i, k);
    }
}

// ---- pass 2: one block per bucket; 5 threads/point, 64 points per sweep ----
__global__ __launch_bounds__(320) void gather_kernel(
    const float* __restrict__ x, const float* __restrict__ grid,
    float* __restrict__ out, const u32* __restrict__ cnt,
    const u32* __restrict__ bucket)
{
    // XCD-chunked bijective swizzle (NBUCK % 8 == 0): each XCD's blocks walk
    // a contiguous raster range of buckets -> neighboring 58KB grid regions
    // stay hot in that XCD's private L2.
    int bid = blockIdx.x;
    int b = (bid & 7) * (NBUCK / 8) + (bid >> 3);

    u32 n = cnt[b];
    if (n > BCAP) n = BCAP;

    int tid = threadIdx.x;        // 0..319
    int lp  = tid / 5;            // local point 0..63
    int k   = tid - lp * 5;       // chunk 0..4

    for (u32 base = 0; base < n; base += 64) {
        u32 p = base + (u32)lp;
        if (p < n) {
            int i = (int)bucket[(size_t)b * BCAP + p];
            compute_chunk(x, grid, out, i, k);
        }
    }
}

// ---- fallback: the verified round-0 kernel (used only if ws too small) -----
__global__ __launch_bounds__(320) void naive_kernel(
    const float* __restrict__ x, const float* __restrict__ grid,
    float* __restrict__ out, int N)
{
    int tid = threadIdx.x;
    int lp  = tid / 5;
    int k   = tid - lp * 5;
    int i   = blockIdx.x * 64 + lp;
    if (i >= N) return;
    compute_chunk(x, grid, out, i, k);
}

extern "C" void kernel_launch(void* const* d_in, const int* in_sizes, int n_in,
                              void* d_out, int out_size, void* d_ws, size_t ws_size,
                              hipStream_t stream) {
    const float* x = (const float*)d_in[0];
    const float* grid = (const float*)d_in[1];
    float* out = (float*)d_out;
    int N = in_sizes[0] / 3;

    size_t need = (size_t)NBUCK * 4 + (size_t)NBUCK * BCAP * 4;  // ~8.4 MB
    if (d_ws == nullptr || ws_size < need) {
        int nblocks = (N + 63) / 64;
        naive_kernel<<<nblocks, 320, 0, stream>>>(x, grid, out, N);
        return;
    }

    u32* cnt = (u32*)d_ws;
    u32* bucket = cnt + NBUCK;

    hipMemsetAsync(cnt, 0, (size_t)NBUCK * 4, stream);
    bin_kernel<<<(N + 255) / 256, 256, 0, stream>>>(x, grid, out, cnt, bucket, N);
    gather_kernel<<<NBUCK, 320, 0, stream>>>(x, grid, out, cnt, bucket);
}

// Round 6
// 396.185 us; speedup vs baseline: 1.0501x; 1.0501x over previous
//
#include <hip/hip_runtime.h>

#define V 128
#define D 20
#define NUM_EMB (V * V * V)

typedef float v4f __attribute__((ext_vector_type(4)));

// Direct-to-LDS gather: per-lane GLOBAL address, LDS dest = wave-uniform
// base + lane*16 (m104). No VGPR destinations -> the register allocator
// cannot collapse outstanding loads (the failure mode of rounds 0-1, where
// 8 declared loads were re-rolled into ~4 recycled registers).
typedef const __attribute__((address_space(1))) void gv_t;
typedef __attribute__((address_space(3))) void lv_t;
#define G2L(gsrc, ldst) \
    __builtin_amdgcn_global_load_lds((gv_t*)(gsrc), (lv_t*)(ldst), 16, 0, 0)

// Block = 256 threads = 4 waves; 20KB LDS -> 8 blocks/CU -> full 32-wave
// occupancy. Each wave independently processes 8 points per iteration:
//   stage:   lane=(point 0..7, corner 0..7) computes the clamped corner row
//            address; 5 x global_load_lds stage chunk k of all 64 rows into
//            slab k (1KB each) -> 320 16B-gathers in flight per wave.
//   consume: lanes 0..39 = (point 0..7, chunk 0..4); 8 x ds_read_b128 with
//            rotated corner order to spread LDS bank groups; trilerp; store.
__global__ __launch_bounds__(256) void dense_grid_enc_kernel(
    const float* __restrict__ x, const float* __restrict__ grid,
    float* __restrict__ out, int N)
{
    __shared__ float lds[4 * 5 * 256];   // [wave][slab k][64 rows x 4 floats]

    const int tid  = threadIdx.x;
    const int wave = tid >> 6;
    const int lane = tid & 63;
    float* wlds = &lds[wave * 5 * 256];

    const int sp = lane >> 3;            // staging point 0..7
    const int sc = lane & 7;             // staging corner 0..7
    const int cp = lane / 5;             // consume point (valid when lane<40)
    const int ck = lane - cp * 5;        // consume chunk 0..4
    const int csrc = (cp & 7) * 8;       // lane holding consume-point's coords

    const int ngroups = (N + 7) >> 3;
    const int nwaves  = (int)gridDim.x * 4;

    for (int g = blockIdx.x * 4 + wave; g < ngroups; g += nwaves) {
        const int gbase = g << 3;

        // ---- address phase (all 64 lanes active: no divergence at issue) ----
        int i_s = gbase + sp;
        if (i_s > N - 1) i_s = N - 1;    // tail: duplicate last point, store-guarded
        float px = x[3 * i_s + 0];
        float py = x[3 * i_s + 1];
        float pz = x[3 * i_s + 2];
        // gp = floor((p+1)*64); cell spacing is exactly 1/64 in fp32
        int ix = (int)floorf((px + 1.0f) * 64.0f);
        int iy = (int)floorf((py + 1.0f) * 64.0f);
        int iz = (int)floorf((pz + 1.0f) * 64.0f);
        int f = ix + iy * V + iz * (V * V)
              + (sc & 1) + ((sc >> 1) & 1) * V + ((sc >> 2) & 1) * (V * V);
        if (f > NUM_EMB - 1) f = NUM_EMB - 1;   // JAX gather OOB clamp
        const float* gp = grid + (size_t)f * D;

        // ---- stage: 5 x 1KB direct-to-LDS gathers (literal size=16) ----
        G2L(gp,      wlds + 0 * 256);
        G2L(gp + 4,  wlds + 1 * 256);
        G2L(gp + 8,  wlds + 2 * 256);
        G2L(gp + 12, wlds + 3 * 256);
        G2L(gp + 16, wlds + 4 * 256);

        // consume-lane coords via shuffle (no x re-read; overlaps the gathers)
        float qx = __shfl(px, csrc, 64);
        float qy = __shfl(py, csrc, 64);
        float qz = __shfl(pz, csrc, 64);

        // Wait own wave's staging (vmcnt(0); exp/lgkm unconstrained), then
        // fence the scheduler: ds_reads below must not hoist above the wait
        // (the compiler does not model the global_load_lds -> LDS dependence).
        __builtin_amdgcn_s_waitcnt(0x0F70);
        __builtin_amdgcn_sched_barrier(0);

        if (lane < 40) {
            float gx = (qx + 1.0f) * 64.0f;
            float gy = (qy + 1.0f) * 64.0f;
            float gz = (qz + 1.0f) * 64.0f;
            float fx = gx - floorf(gx);
            float fy = gy - floorf(gy);
            float fz = gz - floorf(gz);

            const float* slab = wlds + ck * 256;
            v4f acc = (v4f)(0.0f);
            #pragma unroll
            for (int j = 0; j < 8; j++) {
                int c = (j + cp + ck) & 7;   // rotation spreads bank groups
                v4f q = *(const v4f*)(slab + (cp * 8 + c) * 4);
                // selects, not runtime-indexed arrays (those go to scratch)
                float w = ((c & 1) ? fx : 1.0f - fx)
                        * (((c >> 1) & 1) ? fy : 1.0f - fy)
                        * (((c >> 2) & 1) ? fz : 1.0f - fz);
                acc += w * q;
            }
            int i = gbase + cp;
            if (i < N)
                __builtin_nontemporal_store(acc, (v4f*)(out + (size_t)i * D + ck * 4));
        }
        // By loop-back all issued ds_reads have been waited (compiler-counted
        // lgkmcnt before each use), so next iteration may overwrite the slabs.
    }
}

extern "C" void kernel_launch(void* const* d_in, const int* in_sizes, int n_in,
                              void* d_out, int out_size, void* d_ws, size_t ws_size,
                              hipStream_t stream) {
    const float* x = (const float*)d_in[0];
    const float* grid = (const float*)d_in[1];
    float* out = (float*)d_out;
    int N = in_sizes[0] / 3;

    // 2048 blocks x 4 waves = 8192 waves; 8 blocks/CU (LDS-exact) across
    // 256 CUs; each wave grid-strides ~15 groups of 8 points.
    int ngroups = (N + 7) / 8;
    int nblocks = 2048;
    if (nblocks > ngroups) nblocks = ngroups;
    dense_grid_enc_kernel<<<nblocks, 256, 0, stream>>>(x, grid, out, N);
}

// Round 7
// 395.784 us; speedup vs baseline: 1.0511x; 1.0010x over previous
//
#include <hip/hip_runtime.h>

#define V 128
#define D 20
#define NUM_EMB (V * V * V)
#define NBUCK 4096        // 16^3 coarse blocks of 8^3 cells
#define BCAP  512         // slots/bucket; mean 244, sd ~16
#define OVFCAP 4096       // overflow list capacity (statistically never used)
#define REG_ROWS 729      // 9*9*9 grid rows per region
#define REG_CHUNKS 3645   // 729 rows * 5 chunks of 16B
#define STAGE_INSTS 57    // ceil(3645/64) wave-wide load_lds instructions

typedef float v4f __attribute__((ext_vector_type(4)));
typedef unsigned int u32;

// Direct-to-LDS: per-lane GLOBAL src, LDS dest = wave-uniform base + lane*16.
typedef const __attribute__((address_space(1))) void gv_t;
typedef __attribute__((address_space(3))) void lv_t;
#define G2L(gsrc, ldst) \
    __builtin_amdgcn_global_load_lds((gv_t*)(gsrc), (lv_t*)(ldst), 16, 0, 0)

// ---- per-(point,chunk) direct-from-global compute (R0-verified body). Used
// by the naive fallback, the overflow kernel, and bin's last-resort path. ----
__device__ __forceinline__ void compute_chunk(
    const float* __restrict__ x, const float* __restrict__ grid,
    float* __restrict__ out, int i, int k)
{
    float px = x[3 * i + 0];
    float py = x[3 * i + 1];
    float pz = x[3 * i + 2];
    int ix = (int)floorf((px + 1.0f) * 64.0f);
    int iy = (int)floorf((py + 1.0f) * 64.0f);
    int iz = (int)floorf((pz + 1.0f) * 64.0f);

    float x1 = (float)ix * (2.0f / 128.0f) - 1.0f;
    float x2 = (float)(ix + 1) * (2.0f / 128.0f) - 1.0f;
    float y1 = (float)iy * (2.0f / 128.0f) - 1.0f;
    float y2 = (float)(iy + 1) * (2.0f / 128.0f) - 1.0f;
    float z1 = (float)iz * (2.0f / 128.0f) - 1.0f;
    float z2 = (float)(iz + 1) * (2.0f / 128.0f) - 1.0f;

    float wx1 = (px - x1) * 64.0f, wx0 = (x2 - px) * 64.0f;
    float wy1 = (py - y1) * 64.0f, wy0 = (y2 - py) * 64.0f;
    float wz1 = (pz - z1) * 64.0f, wz0 = (z2 - pz) * 64.0f;

    int f000 = ix + iy * V + iz * V * V;
    int flats[8] = { f000,             f000 + 1,
                     f000 + V,         f000 + V + 1,
                     f000 + V * V,     f000 + V * V + 1,
                     f000 + V * V + V, f000 + V * V + V + 1 };
    #pragma unroll
    for (int c = 0; c < 8; c++)
        if (flats[c] > NUM_EMB - 1) flats[c] = NUM_EMB - 1;

    float w[8];
    w[0] = wx0 * wy0 * wz0; w[1] = wx1 * wy0 * wz0;
    w[2] = wx0 * wy1 * wz0; w[3] = wx1 * wy1 * wz0;
    w[4] = wx0 * wy0 * wz1; w[5] = wx1 * wy0 * wz1;
    w[6] = wx0 * wy1 * wz1; w[7] = wx1 * wy1 * wz1;

    v4f q[8];
    #pragma unroll
    for (int c = 0; c < 8; c++)
        q[c] = *(const v4f*)(grid + (size_t)flats[c] * D + 4 * k);

    v4f acc = (v4f)(0.0f);
    #pragma unroll
    for (int c = 0; c < 8; c++) acc += w[c] * q[c];

    __builtin_nontemporal_store(acc, (v4f*)(out + (size_t)i * D + 4 * k));
}

// ---- pass 1: bin points by 8^3-cell block (lean: no grid traffic) ---------
__global__ __launch_bounds__(256) void bin_kernel(
    const float* __restrict__ x, const float* __restrict__ grid,
    float* __restrict__ out, u32* __restrict__ cnt, u32* __restrict__ blist,
    u32* __restrict__ ovfc, u32* __restrict__ ovf, int N)
{
    int i = blockIdx.x * 256 + threadIdx.x;
    if (i >= N) return;
    float px = x[3 * i + 0];
    float py = x[3 * i + 1];
    float pz = x[3 * i + 2];
    int ix = (int)floorf((px + 1.0f) * 64.0f);
    int iy = (int)floorf((py + 1.0f) * 64.0f);
    int iz = (int)floorf((pz + 1.0f) * 64.0f);
    int b = (ix >> 3) + ((iy >> 3) << 4) + ((iz >> 3) << 8);
    u32 pos = atomicAdd(&cnt[b], 1u);
    if (pos < BCAP) {
        blist[(size_t)b * BCAP + pos] = (u32)i;
    } else {
        u32 op = atomicAdd(ovfc, 1u);
        if (op < OVFCAP) ovf[op] = (u32)i;
        else for (int k = 0; k < 5; k++) compute_chunk(x, grid, out, i, k);
    }
}

// ---- pass 2: one block per bucket. Stage the bucket's 9^3-row grid region
// (58.3KB) into LDS with coalesced global_load_lds bursts; every point-gather
// becomes a ds_read_b128. One vmcnt drain per BUCKET (R6's per-8-point drain
// was the mistake), amortized over ~244 points of LDS-fed compute. -----------
__global__ __launch_bounds__(256) void gather_kernel(
    const float* __restrict__ x, const float* __restrict__ grid,
    float* __restrict__ out, const u32* __restrict__ cnt,
    const u32* __restrict__ blist)
{
    // 14640 floats = 58560B (3645 chunks + pad for the 3 overshoot lanes).
    __shared__ __align__(16) float reg[14640];

    // XCD-chunked bijective swizzle (4096 % 8 == 0): each XCD walks a
    // contiguous raster range of buckets -> neighboring regions share planes.
    int bid = blockIdx.x;
    int b = (bid & 7) * (NBUCK / 8) + (bid >> 3);
    int bx = b & 15, by = (b >> 4) & 15, bz = b >> 8;
    int gx0 = bx * 8, gy0 = by * 8, gz0 = bz * 8;

    int tid = threadIdx.x, wave = tid >> 6, lane = tid & 63;

    // ---- stage: region rows addressed by FLAT index with carry, final
    // clamp to NUM_EMB-1 -> byte-identical to the reference's flat-index
    // arithmetic at block borders (ix+1==128 wraps into iy+1, etc.).
    for (int w = wave; w < STAGE_INSTS; w += 4) {
        int t = w * 64 + lane;
        if (t > REG_CHUNKS - 1) t = REG_CHUNKS - 1;  // dest lands in LDS pad
        int row = t / 5;             // region row 0..728
        int c   = t - row * 5;       // 16B chunk 0..4 within the 80B row
        int sx = row % 9;
        int r9 = row / 9;
        int sy = r9 % 9;
        int sz = r9 / 9;
        int flat = (gx0 + sx) + (gy0 + sy) * V + (gz0 + sz) * (V * V);
        if (flat > NUM_EMB - 1) flat = NUM_EMB - 1;  // JAX OOB clamp
        // LDS dest: uniform base reg+w*256 floats; HW adds lane*16B -> t*16B.
        G2L(grid + (size_t)flat * D + c * 4, reg + w * 256);
    }

    // Implicit s_waitcnt vmcnt(0) before s_barrier covers all load_lds.
    __syncthreads();

    // ---- consume: 5 consecutive threads per point (same-x broadcast load),
    // 8 x ds_read_b128 per thread from the LDS region.
    u32 n = cnt[b];
    if (n > BCAP) n = BCAP;
    int total = (int)n * 5;
    for (int u = tid; u < total; u += 256) {
        int p = u / 5;
        int k = u - p * 5;
        int i = (int)blist[(size_t)b * BCAP + p];
        float px = x[3 * i + 0];
        float py = x[3 * i + 1];
        float pz = x[3 * i + 2];
        float gxf = (px + 1.0f) * 64.0f;
        float gyf = (py + 1.0f) * 64.0f;
        float gzf = (pz + 1.0f) * 64.0f;
        float ixf = floorf(gxf), iyf = floorf(gyf), izf = floorf(gzf);
        float fx = gxf - ixf;   // == (px-x1)*64 (R1-verified numerics)
        float fy = gyf - iyf;
        float fz = gzf - izf;
        int lx = (int)ixf - gx0;    // 0..7 by construction of the binning
        int ly = (int)iyf - gy0;
        int lz = (int)izf - gz0;
        int l000 = (lz * 9 + ly) * 9 + lx;

        v4f acc = (v4f)(0.0f);
        #pragma unroll
        for (int c = 0; c < 8; c++) {
            int l = l000 + (c & 1) + ((c >> 1) & 1) * 9 + ((c >> 2) & 1) * 81;
            v4f q = *(const v4f*)(reg + l * 20 + k * 4);
            float wgt = ((c & 1)        ? fx : 1.0f - fx)
                      * (((c >> 1) & 1) ? fy : 1.0f - fy)
                      * (((c >> 2) & 1) ? fz : 1.0f - fz);
            acc += wgt * q;
        }
        __builtin_nontemporal_store(acc, (v4f*)(out + (size_t)i * D + k * 4));
    }
}

// ---- pass 3: drain the overflow list (statistically empty; ~2us) -----------
__global__ __launch_bounds__(256) void ovf_kernel(
    const float* __restrict__ x, const float* __restrict__ grid,
    float* __restrict__ out, const u32* __restrict__ ovfc,
    const u32* __restrict__ ovf)
{
    u32 n = *ovfc;
    if (n > OVFCAP) n = OVFCAP;
    int total = (int)n * 5;
    for (int u = blockIdx.x * 256 + threadIdx.x; u < total;
         u += 256 * (int)gridDim.x) {
        int p = u / 5;
        int k = u - p * 5;
        compute_chunk(x, grid, out, (int)ovf[p], k);
    }
}

// ---- fallback: verified round-0 kernel (used only if ws too small) ---------
__global__ __launch_bounds__(320) void naive_kernel(
    const float* __restrict__ x, const float* __restrict__ grid,
    float* __restrict__ out, int N)
{
    int tid = threadIdx.x;
    int lp  = tid / 5;
    int k   = tid - lp * 5;
    int i   = blockIdx.x * 64 + lp;
    if (i >= N) return;
    compute_chunk(x, grid, out, i, k);
}

extern "C" void kernel_launch(void* const* d_in, const int* in_sizes, int n_in,
                              void* d_out, int out_size, void* d_ws, size_t ws_size,
                              hipStream_t stream) {
    const float* x = (const float*)d_in[0];
    const float* grid = (const float*)d_in[1];
    float* out = (float*)d_out;
    int N = in_sizes[0] / 3;

    // ws: [cnt 4096][ovfc 1][ovf 4096][blist 4096*512] u32 = ~8.42 MB
    size_t need = ((size_t)NBUCK + 1 + OVFCAP + (size_t)NBUCK * BCAP) * 4;
    if (d_ws == nullptr || ws_size < need) {
        int nblocks = (N + 63) / 64;
        naive_kernel<<<nblocks, 320, 0, stream>>>(x, grid, out, N);
        return;
    }

    u32* cnt   = (u32*)d_ws;
    u32* ovfc  = cnt + NBUCK;
    u32* ovf   = ovfc + 1;
    u32* blist = ovf + OVFCAP;

    hipMemsetAsync(cnt, 0, (size_t)(NBUCK + 1) * 4, stream);  // cnt + ovfc
    bin_kernel<<<(N + 255) / 256, 256, 0, stream>>>(
        x, grid, out, cnt, blist, ovfc, ovf, N);
    gather_kernel<<<NBUCK, 256, 0, stream>>>(x, grid, out, cnt, blist);
    ovf_kernel<<<16, 256, 0, stream>>>(x, grid, out, ovfc, ovf);
}

// Round 8
// 388.549 us; speedup vs baseline: 1.0707x; 1.0186x over previous
//
#include <hip/hip_runtime.h>

#define V 128
#define D 20
#define NUM_EMB (V * V * V)
#define NBUCK 32768       // 32^3 coarse blocks of 4^3 cells
#define BCAP  60          // slots/bucket; mean 30.5, sd 5.5 (+5.4 sigma)
#define OVFCAP 16384      // overflow list (handles the Poisson tail correctly)
#define REG_ROWS 125      // 5*5*5 grid rows per region
#define REG_CHUNKS 625    // 125 rows * 5 chunks of 16B
#define STAGE_INSTS 10    // ceil(625/64) wave-wide load_lds instructions

typedef float v4f __attribute__((ext_vector_type(4)));
typedef unsigned int u32;

// Direct-to-LDS: per-lane GLOBAL src, LDS dest = wave-uniform base + lane*16.
typedef const __attribute__((address_space(1))) void gv_t;
typedef __attribute__((address_space(3))) void lv_t;
#define G2L(gsrc, ldst) \
    __builtin_amdgcn_global_load_lds((gv_t*)(gsrc), (lv_t*)(ldst), 16, 0, 0)

// ---- per-(point,chunk) direct-from-global compute (R0-verified body). ----
__device__ __forceinline__ void compute_chunk(
    const float* __restrict__ x, const float* __restrict__ grid,
    float* __restrict__ out, int i, int k)
{
    float px = x[3 * i + 0];
    float py = x[3 * i + 1];
    float pz = x[3 * i + 2];
    int ix = (int)floorf((px + 1.0f) * 64.0f);
    int iy = (int)floorf((py + 1.0f) * 64.0f);
    int iz = (int)floorf((pz + 1.0f) * 64.0f);

    float x1 = (float)ix * (2.0f / 128.0f) - 1.0f;
    float x2 = (float)(ix + 1) * (2.0f / 128.0f) - 1.0f;
    float y1 = (float)iy * (2.0f / 128.0f) - 1.0f;
    float y2 = (float)(iy + 1) * (2.0f / 128.0f) - 1.0f;
    float z1 = (float)iz * (2.0f / 128.0f) - 1.0f;
    float z2 = (float)(iz + 1) * (2.0f / 128.0f) - 1.0f;

    float wx1 = (px - x1) * 64.0f, wx0 = (x2 - px) * 64.0f;
    float wy1 = (py - y1) * 64.0f, wy0 = (y2 - py) * 64.0f;
    float wz1 = (pz - z1) * 64.0f, wz0 = (z2 - pz) * 64.0f;

    int f000 = ix + iy * V + iz * V * V;
    int flats[8] = { f000,             f000 + 1,
                     f000 + V,         f000 + V + 1,
                     f000 + V * V,     f000 + V * V + 1,
                     f000 + V * V + V, f000 + V * V + V + 1 };
    #pragma unroll
    for (int c = 0; c < 8; c++)
        if (flats[c] > NUM_EMB - 1) flats[c] = NUM_EMB - 1;

    float w[8];
    w[0] = wx0 * wy0 * wz0; w[1] = wx1 * wy0 * wz0;
    w[2] = wx0 * wy1 * wz0; w[3] = wx1 * wy1 * wz0;
    w[4] = wx0 * wy0 * wz1; w[5] = wx1 * wy0 * wz1;
    w[6] = wx0 * wy1 * wz1; w[7] = wx1 * wy1 * wz1;

    v4f q[8];
    #pragma unroll
    for (int c = 0; c < 8; c++)
        q[c] = *(const v4f*)(grid + (size_t)flats[c] * D + 4 * k);

    v4f acc = (v4f)(0.0f);
    #pragma unroll
    for (int c = 0; c < 8; c++) acc += w[c] * q[c];

    __builtin_nontemporal_store(acc, (v4f*)(out + (size_t)i * D + 4 * k));
}

// ---- pass 1: bin points by 4^3-cell block ---------------------------------
__global__ __launch_bounds__(256) void bin_kernel(
    const float* __restrict__ x, const float* __restrict__ grid,
    float* __restrict__ out, u32* __restrict__ cnt, u32* __restrict__ blist,
    u32* __restrict__ ovfc, u32* __restrict__ ovf, int N)
{
    int i = blockIdx.x * 256 + threadIdx.x;
    if (i >= N) return;
    float px = x[3 * i + 0];
    float py = x[3 * i + 1];
    float pz = x[3 * i + 2];
    int ix = (int)floorf((px + 1.0f) * 64.0f);
    int iy = (int)floorf((py + 1.0f) * 64.0f);
    int iz = (int)floorf((pz + 1.0f) * 64.0f);
    int b = (ix >> 2) + ((iy >> 2) << 5) + ((iz >> 2) << 10);
    u32 pos = atomicAdd(&cnt[b], 1u);
    if (pos < BCAP) {
        blist[(size_t)b * BCAP + pos] = (u32)i;
    } else {
        u32 op = atomicAdd(ovfc, 1u);
        if (op < OVFCAP) ovf[op] = (u32)i;
        else for (int k = 0; k < 5; k++) compute_chunk(x, grid, out, i, k);
    }
}

// ---- pass 2: one 128-thread block per bucket. Stage the bucket's 5^3-row
// region (10KB) into LDS via coalesced global_load_lds; consume from LDS.
// Small LDS footprint -> ~11-16 resident blocks/CU, so plain TLP hides the
// per-block vmcnt(0)+barrier drain (R7's 58.8KB regions allowed only 2
// resident blocks -> the memory queue emptied at every barrier). -------------
__global__ __launch_bounds__(128) void gather_kernel(
    const float* __restrict__ x, const float* __restrict__ grid,
    float* __restrict__ out, const u32* __restrict__ cnt,
    const u32* __restrict__ blist)
{
    // 10 stage-insts x 256 floats = 2560 floats = 10,240B (625 chunks + pad)
    __shared__ __align__(16) float reg[STAGE_INSTS * 256];

    // XCD-chunked bijective swizzle (32768 % 8 == 0): each XCD walks a
    // contiguous raster range -> neighboring regions share overlap planes
    // in that XCD's private L2 (half the staged bytes are such re-reads).
    int bid = blockIdx.x;
    int b = (bid & 7) * (NBUCK / 8) + (bid >> 3);
    int bx = b & 31, by = (b >> 5) & 31, bz = b >> 10;
    int gx0 = bx * 4, gy0 = by * 4, gz0 = bz * 4;

    int tid = threadIdx.x, wave = tid >> 6, lane = tid & 63;

    // ---- stage: region rows addressed by FLAT index with carry + final
    // clamp -> byte-identical to the reference's flat-index arithmetic at
    // borders (verified at 8^3 granularity in R7, absmax 2.44e-4).
    for (int w = wave; w < STAGE_INSTS; w += 2) {
        int t = w * 64 + lane;
        if (t > REG_CHUNKS - 1) t = REG_CHUNKS - 1;  // src clamp; dest = pad
        int row = t / 5;             // region row 0..124
        int c   = t - row * 5;       // 16B chunk 0..4 within the 80B row
        int sx = row % 5;
        int r5 = row / 5;
        int sy = r5 % 5;
        int sz = r5 / 5;
        int flat = (gx0 + sx) + (gy0 + sy) * V + (gz0 + sz) * (V * V);
        if (flat > NUM_EMB - 1) flat = NUM_EMB - 1;  // JAX OOB clamp
        G2L(grid + (size_t)flat * D + c * 4, reg + w * 256);
    }

    // Implicit s_waitcnt vmcnt(0) before s_barrier covers all load_lds.
    __syncthreads();

    // ---- consume: 5 consecutive threads per point, 8 x ds_read_b128 each.
    u32 n = cnt[b];
    if (n > BCAP) n = BCAP;
    int total = (int)n * 5;
    for (int u = tid; u < total; u += 128) {
        int p = u / 5;
        int k = u - p * 5;
        int i = (int)blist[(size_t)b * BCAP + p];
        float px = x[3 * i + 0];
        float py = x[3 * i + 1];
        float pz = x[3 * i + 2];
        float gxf = (px + 1.0f) * 64.0f;
        float gyf = (py + 1.0f) * 64.0f;
        float gzf = (pz + 1.0f) * 64.0f;
        float ixf = floorf(gxf), iyf = floorf(gyf), izf = floorf(gzf);
        float fx = gxf - ixf;   // == (px-x1)*64 (verified numerics)
        float fy = gyf - iyf;
        float fz = gzf - izf;
        int lx = (int)ixf - gx0;    // 0..3 by construction of the binning
        int ly = (int)iyf - gy0;
        int lz = (int)izf - gz0;
        int l000 = (lz * 5 + ly) * 5 + lx;

        v4f acc = (v4f)(0.0f);
        #pragma unroll
        for (int c = 0; c < 8; c++) {
            int l = l000 + (c & 1) + ((c >> 1) & 1) * 5 + ((c >> 2) & 1) * 25;
            v4f q = *(const v4f*)(reg + l * 20 + k * 4);
            float wgt = ((c & 1)        ? fx : 1.0f - fx)
                      * (((c >> 1) & 1) ? fy : 1.0f - fy)
                      * (((c >> 2) & 1) ? fz : 1.0f - fz);
            acc += wgt * q;
        }
        __builtin_nontemporal_store(acc, (v4f*)(out + (size_t)i * D + k * 4));
    }
}

// ---- pass 3: drain the overflow list (Poisson tail; a few points at most) --
__global__ __launch_bounds__(256) void ovf_kernel(
    const float* __restrict__ x, const float* __restrict__ grid,
    float* __restrict__ out, const u32* __restrict__ ovfc,
    const u32* __restrict__ ovf)
{
    u32 n = *ovfc;
    if (n > OVFCAP) n = OVFCAP;
    int total = (int)n * 5;
    for (int u = blockIdx.x * 256 + threadIdx.x; u < total;
         u += 256 * (int)gridDim.x) {
        int p = u / 5;
        int k = u - p * 5;
        compute_chunk(x, grid, out, (int)ovf[p], k);
    }
}

// ---- fallback: verified round-0 kernel (used only if ws too small) ---------
__global__ __launch_bounds__(320) void naive_kernel(
    const float* __restrict__ x, const float* __restrict__ grid,
    float* __restrict__ out, int N)
{
    int tid = threadIdx.x;
    int lp  = tid / 5;
    int k   = tid - lp * 5;
    int i   = blockIdx.x * 64 + lp;
    if (i >= N) return;
    compute_chunk(x, grid, out, i, k);
}

extern "C" void kernel_launch(void* const* d_in, const int* in_sizes, int n_in,
                              void* d_out, int out_size, void* d_ws, size_t ws_size,
                              hipStream_t stream) {
    const float* x = (const float*)d_in[0];
    const float* grid = (const float*)d_in[1];
    float* out = (float*)d_out;
    int N = in_sizes[0] / 3;

    // ws: [cnt 32768][ovfc 1][ovf 16384][blist 32768*60] u32 = ~8.06 MB
    // (less than R7's proven-available 8.42 MB)
    size_t need = ((size_t)NBUCK + 1 + OVFCAP + (size_t)NBUCK * BCAP) * 4;
    if (d_ws == nullptr || ws_size < need) {
        int nblocks = (N + 63) / 64;
        naive_kernel<<<nblocks, 320, 0, stream>>>(x, grid, out, N);
        return;
    }

    u32* cnt   = (u32*)d_ws;
    u32* ovfc  = cnt + NBUCK;
    u32* ovf   = ovfc + 1;
    u32* blist = ovf + OVFCAP;

    hipMemsetAsync(cnt, 0, (size_t)(NBUCK + 1) * 4, stream);  // cnt + ovfc
    bin_kernel<<<(N + 255) / 256, 256, 0, stream>>>(
        x, grid, out, cnt, blist, ovfc, ovf, N);
    gather_kernel<<<NBUCK, 128, 0, stream>>>(x, grid, out, cnt, blist);
    ovf_kernel<<<16, 256, 0, stream>>>(x, grid, out, ovfc, ovf);
}